// Round 4
// baseline (212.274 us; speedup 1.0000x reference)
//
#include <hip/hip_runtime.h>

#define B_ 512
#define T_ 512
#define C_ 128
#define L_ 80
#define BLANK_ 127
#define EPS_ 1e-7f
#define LN2_ 0.6931471805599453f

// raw v_log_f32 (base-2); __log2f collides with glibc math.h reserved names.
#define LOG2F(x) __builtin_amdgcn_logf(x)

// DPP cross-lane ops (VALU pipe).
template <int CTRL>
__device__ __forceinline__ int dpp_i(int x) {
  return __builtin_amdgcn_update_dpp(0, x, CTRL, 0xF, 0xF, true);
}
template <int CTRL>
__device__ __forceinline__ float dpp_f(float x) {
  return __int_as_float(
      __builtin_amdgcn_update_dpp(0, __float_as_int(x), CTRL, 0xF, 0xF, true));
}
#define DPP_WSHR1 0x138   // wave shift right 1 == shfl_up(1); lane0 -> 0
#define DPP_XOR1  0xB1    // quad_perm [1,0,3,2]
#define DPP_XOR2  0x4E    // quad_perm [2,3,0,1]
#define DPP_HMIRR 0x141   // row_half_mirror (within 8)
#define DPP_MIRR  0x140   // row_mirror (within 16)

// DECOUPLED design — no producer->consumer LDS ring, no per-phase barriers.
// Rounds 1-3 showed every schedule that couples global-load issue to the DP
// cadence (barriered or not) self-limits at ~3.6 TB/s. Here the two sides
// free-run:
//   waves 1-3: pure streamers. Own every-3rd 8-row block, 3-deep float4
//     register pipeline (12 float4 in flight/wave; 6 waves/CU = 72 KB/CU
//     outstanding >> BW*latency), fold EPS + row-sum + log2 (denominator).
//     No sync with wave 0 at all.
//   wave 0: self-paced DP. Gathers its 3 columns (ea, eb, blank) per row
//     DIRECTLY from global: 64 lanes scatter within one 512B row -> ~4-5
//     cache lines, L2/L3-warm from the streamers. 3-set software pipeline
//     (2-group lead, 24 dword loads/group). DP math is bitwise-identical
//     to the verified absmax=0 kernel (EPS added after load = same fadd).
// ONE __syncthreads at the end to combine the denominator partials.
__global__ __launch_bounds__(256) void ctc_fused(
    const int* __restrict__ labels,     // [B,L]
    const float* __restrict__ y_pred,   // [B,T,C]
    float* __restrict__ out)            // [B,1]
{
  const int b = blockIdx.x, tid = threadIdx.x;
  const int wid = tid >> 6, lane = tid & 63;
  const float* gp = y_pred + (size_t)b * T_ * C_;

  __shared__ float comb[4];             // streamers' Sacc partials (1..3)

  const bool evenLane = ((lane & 1) == 0);

  float A0 = 0.f, A1 = 0.f, A2 = 0.f;   // DP state (wave 0)
  int E = 0;                            // per-lane scale: stored = true * 2^E

  if (wid == 0) {
    // ---- DP wave: static per-lane symbols + skip masks (verified math) ----
    // even lane i: states blank / label k1=3i/2 / blank
    // odd  lane i: states label k0=(3i-1)/2 / blank / label k2=k0+1
    auto labAt = [&](int k) -> int {
      return (k >= 0 && k < L_) ? labels[b * L_ + k] : BLANK_;
    };
    int ea, eb;
    float m0, m1, m2;                   // allow-skip masks as 0.0/1.0
    if (evenLane) {
      const int k1 = (3 * lane) >> 1;
      ea = labAt(k1); eb = ea;
      m0 = 0.f; m2 = 0.f;
      m1 = ((k1 < L_) && (k1 == 0 || ea != labAt(k1 - 1))) ? 1.f : 0.f;
    } else {
      const int k0 = (3 * lane - 1) >> 1;
      const int k2 = k0 + 1;
      ea = labAt(k0); eb = labAt(k2);
      m0 = ((k0 < L_) && (k0 == 0 || ea != labAt(k0 - 1))) ? 1.f : 0.f;
      m1 = 0.f;
      m2 = ((k2 < L_) && (eb != ea)) ? 1.f : 0.f;
    }
    // virtual init: one recurrence step from (A0=1@lane0) gives exact alpha(0)
    A0 = (lane == 0) ? 1.f : 0.f;

    const float* pea = gp + ea;         // per-lane column pointers
    const float* peb = gp + eb;
    const float* pbl = gp + BLANK_;

    // 3 named register sets (all indices compile-time -> no scratch, rule #20)
    float gaA[8], gbA[8], pbA[8];
    float gaB[8], gbB[8], pbB[8];
    float gaC[8], gbC[8], pbC[8];

    auto loadG = [&](float (&g)[8], float (&h)[8], float (&p)[8], int t0) {
      #pragma unroll
      for (int j = 0; j < 8; ++j) {
        g[j] = pea[(t0 + j) * C_];
        h[j] = peb[(t0 + j) * C_];
        p[j] = pbl[(t0 + j) * C_];      // same addr all lanes: 1 line
      }
    };
    auto stepG = [&](float (&g)[8], float (&h)[8], float (&p)[8]) {
      const int EL = dpp_i<DPP_WSHR1>(E);   // left lane's exponent (lane0->0)
      const int d = E - EL;             // block-constant reconcile shift
      #pragma unroll
      for (int j = 0; j < 8; ++j) {
        const float p1 = dpp_f<DPP_WSHR1>(A1);   // left A1 (state 3i-2)
        const float p2 = dpp_f<DPP_WSHR1>(A2);   // left A2 (state 3i-1)
        const float p1p = ldexpf(p1, d);
        const float p2p = ldexpf(p2, d);
        const float q0 = (evenLane ? p[j] : g[j]) + EPS_;
        const float q1 = (evenLane ? g[j] : p[j]) + EPS_;
        const float q2 = (evenLane ? p[j] : h[j]) + EPS_;
        const float t0 = q0 * fmaf(m0, p1p, A0 + p2p);
        const float t1 = q1 * fmaf(m1, p2p, A1 + A0);
        const float t2 = q2 * fmaf(m2, A0, A2 + A1);
        A0 = t0; A1 = t1; A2 = t2;
      }
      // per-lane rescale: keep lane max ~2^0, fold into E
      const float mx = fmaxf(fmaxf(A0, A1), A2);
      int ee = (int)((__float_as_uint(mx) >> 23) & 255u) - 127;
      const bool z = (mx == 0.f);
      ee = z ? 0 : ee;
      A0 = ldexpf(A0, -ee); A1 = ldexpf(A1, -ee); A2 = ldexpf(A2, -ee);
      E = z ? EL : (E - ee);            // virgin lanes track left neighbor's E
    };

    // software pipeline: 64 groups of 8 rows, 2-group load lead
    loadG(gaA, gbA, pbA, 0);
    loadG(gaB, gbB, pbB, 8);
    for (int g = 0; g < 63; g += 3) {
      loadG(gaC, gbC, pbC, 8 * (g + 2));
      stepG(gaA, gbA, pbA);             // group g
      loadG(gaA, gbA, pbA, 8 * (g + 3));
      stepG(gaB, gbB, pbB);             // group g+1
      if (g + 4 < 64) loadG(gaB, gbB, pbB, 8 * (g + 4));
      stepG(gaC, gbC, pbC);             // group g+2
    }
    stepG(gaA, gbA, pbA);               // group 63
  } else {
    // ---- streamer wave: every-3rd 8-row block, 3-deep float4 pipeline ----
    const int w = wid - 1;              // 0..2
    const int rgrp = lane >> 3, j16 = lane & 7;
    const int N = (64 - w + 2) / 3;     // owned blocks: w=0 -> 22, else 21
    float4 S0[4], S1[4], S2[4];
    float Sacc = 0.f;                   // per-lane partial: sum log2(rowsum)

    auto loadB = [&](float4 (&S)[4], int i) {   // owned-block index i
      const int blk = w + 3 * i;
      const float4* src =
          (const float4*)(gp + (size_t)(8 * blk + rgrp) * C_) + 4 * j16;
      #pragma unroll
      for (int k = 0; k < 4; ++k) S[k] = src[k];
    };
    auto sumB = [&](float4 (&S)[4]) {   // eps-add + fused row-sum + log2
      float s = 0.f;
      #pragma unroll
      for (int k = 0; k < 4; ++k) {
        float4 v = S[k];
        v.x += EPS_; v.y += EPS_; v.z += EPS_; v.w += EPS_;
        s += (v.x + v.y) + (v.z + v.w);
      }
      s += dpp_f<DPP_XOR1>(s);
      s += dpp_f<DPP_XOR2>(s);
      s += dpp_f<DPP_HMIRR>(s);         // 8 lanes of the row share the sum
      Sacc += LOG2F(s);                 // 8x redundant; divided out at end
    };

    loadB(S0, 0);
    if (1 < N) loadB(S1, 1);
    if (2 < N) loadB(S2, 2);
    for (int i = 0; i < N; i += 3) {
      sumB(S0); if (i + 3 < N) loadB(S0, i + 3);
      if (i + 1 < N) { sumB(S1); if (i + 4 < N) loadB(S1, i + 4); }
      if (i + 2 < N) { sumB(S2); if (i + 5 < N) loadB(S2, i + 5); }
    }

    // denominator partial (each row counted 8x -> *0.125)
    float s = Sacc;
    s += dpp_f<DPP_XOR1>(s);
    s += dpp_f<DPP_XOR2>(s);
    s += dpp_f<DPP_HMIRR>(s);
    s += dpp_f<DPP_MIRR>(s);
    s += __shfl_xor(s, 16, 64);
    s += __shfl_xor(s, 32, 64);
    if (lane == 0) comb[wid] = s * 0.125f;
  }

  __syncthreads();                      // the ONLY workgroup barrier

  // loss = ln2 * (S - (log2(A159+A160) - E));  lane 53: A0=s159, A1=s160
  if (wid == 0 && lane == 53) {
    const float Stot = comb[1] + comb[2] + comb[3];
    out[b] = LN2_ * (Stot - (LOG2F(A0 + A1) - (float)E));
  }
}

extern "C" void kernel_launch(void* const* d_in, const int* in_sizes, int n_in,
                              void* d_out, int out_size, void* d_ws, size_t ws_size,
                              hipStream_t stream) {
  const int*   labels = (const int*)d_in[0];    // y_true [B,L]
  const float* y_pred = (const float*)d_in[1];  // y_pred [B,T,C]
  float*       out    = (float*)d_out;          // [B,1]
  ctc_fused<<<dim3(B_), dim3(256), 0, stream>>>(labels, y_pred, out);
}

// Round 5
// 193.965 us; speedup vs baseline: 1.0944x; 1.0944x over previous
//
#include <hip/hip_runtime.h>

#define B_ 512
#define T_ 512
#define C_ 128
#define L_ 80
#define BLANK_ 127
#define EPS_ 1e-7f
#define LN2_ 0.6931471805599453f
#define RING_ 16    // ring depth in 8-row blocks (64 KB LDS)

// raw v_log_f32 (base-2); __log2f collides with glibc math.h reserved names.
#define LOG2F(x) __builtin_amdgcn_logf(x)

// DPP cross-lane ops (VALU pipe).
template <int CTRL>
__device__ __forceinline__ int dpp_i(int x) {
  return __builtin_amdgcn_update_dpp(0, x, CTRL, 0xF, 0xF, true);
}
template <int CTRL>
__device__ __forceinline__ float dpp_f(float x) {
  return __int_as_float(
      __builtin_amdgcn_update_dpp(0, __float_as_int(x), CTRL, 0xF, 0xF, true));
}
#define DPP_WSHR1 0x138   // wave shift right 1 == shfl_up(1); lane0 -> 0
#define DPP_XOR1  0xB1    // quad_perm [1,0,3,2]
#define DPP_XOR2  0x4E    // quad_perm [2,3,0,1]
#define DPP_HMIRR 0x141   // row_half_mirror (within 8)
#define DPP_MIRR  0x140   // row_mirror (within 16)

// FREE-RUNNING producer/consumer via deep LDS ring + flag/credit sync.
//
// Rounds 1-3 (barrier-paced) all pinned at ~37us kernel: Little's-law showed
// avg outstanding load bytes/CU ~4.8KB (issue once per phase, retire in
// ~900cy) -> 12.8 GB/s/CU, exactly the measured rate. Memory was DEMAND-
// paced by the phase cadence. Fix: producers issue continuously, gated only
// by ring-slot credit (16 blocks = 64KB/wg ahead), not by the consumer's
// cadence. Per-block ready-flags (acquire/release, workgroup scope) replace
// barriers; ONE __syncthreads total (epilogue combine).
//   wave0: DP consumer (verified forward recurrence, all 512 rows); polls
//     flag[i], gathers 3 cols/row from ring slot i&15, pipelined 1 block
//     ahead; publishes cons=i+1 (relaxed) to return slot credit.
//   waves1-3: producers; own every-3rd block; 2-owned-block register lead
//     (6 blocks ~4800cy >> 900cy HBM latency); wait slot credit
//     (cons >= j-15), then +EPS, row-sum/log2 (denominator), ds_write slot,
//     lgkmcnt(0), release flag[j].
__global__ __launch_bounds__(256) void ctc_fused(
    const int* __restrict__ labels,     // [B,L]
    const float* __restrict__ y_pred,   // [B,T,C]
    float* __restrict__ out)            // [B,1]
{
  const int b = blockIdx.x, tid = threadIdx.x;
  const int wid = tid >> 6, lane = tid & 63;
  const float* gp = y_pred + (size_t)b * T_ * C_;

  __shared__ float ring[RING_ * 1024];  // 16 slots x 8 rows x 128 floats
  __shared__ int   flags[64];           // block i staged?
  __shared__ int   cons;                // blocks fully consumed
  __shared__ float comb[4];             // producers' Sacc partials (1..3)

  if (tid < 64) flags[tid] = 0;
  if (tid == 0) cons = 0;
  __syncthreads();                      // init visible before any traffic

  const bool evenLane = ((lane & 1) == 0);

  if (wid == 0) {
    // ---- DP consumer: static per-lane symbols + skip masks (verified) ----
    // even lane i: states blank / label k1=3i/2 / blank
    // odd  lane i: states label k0=(3i-1)/2 / blank / label k2=k0+1
    auto labAt = [&](int k) -> int {
      return (k >= 0 && k < L_) ? labels[b * L_ + k] : BLANK_;
    };
    int ea, eb;
    float m0, m1, m2;                   // allow-skip masks as 0.0/1.0
    if (evenLane) {
      const int k1 = (3 * lane) >> 1;
      ea = labAt(k1); eb = ea;
      m0 = 0.f; m2 = 0.f;
      m1 = ((k1 < L_) && (k1 == 0 || ea != labAt(k1 - 1))) ? 1.f : 0.f;
    } else {
      const int k0 = (3 * lane - 1) >> 1;
      const int k2 = k0 + 1;
      ea = labAt(k0); eb = labAt(k2);
      m0 = ((k0 < L_) && (k0 == 0 || ea != labAt(k0 - 1))) ? 1.f : 0.f;
      m1 = 0.f;
      m2 = ((k2 < L_) && (eb != ea)) ? 1.f : 0.f;
    }
    // virtual init: one recurrence step from (A0=1@lane0) gives exact alpha(0)
    float A0 = (lane == 0) ? 1.f : 0.f, A1 = 0.f, A2 = 0.f;
    int E = 0;                          // per-lane scale: stored = true * 2^E

    auto waitFlag = [&](int i) {        // uniform: all lanes read same addr
      while (__hip_atomic_load(&flags[i], __ATOMIC_ACQUIRE,
                               __HIP_MEMORY_SCOPE_WORKGROUP) == 0)
        __builtin_amdgcn_s_sleep(2);
    };
    auto consSet = [&](int v) {         // relaxed: freed slot's reads are
      if (lane == 0)                    // 15 blocks stale -> long complete
        __hip_atomic_store(&cons, v, __ATOMIC_RELAXED,
                           __HIP_MEMORY_SCOPE_WORKGROUP);
    };
    auto gath = [&](float (&g)[8], float (&h)[8], float (&p)[8], int i) {
      const float* rs = ring + (i & (RING_ - 1)) * 1024;
      #pragma unroll
      for (int j = 0; j < 8; ++j) {
        g[j] = rs[j * C_ + ea];
        h[j] = rs[j * C_ + eb];
        p[j] = rs[j * C_ + BLANK_];     // same addr all lanes: LDS broadcast
      }
    };
    auto stepG = [&](float (&g)[8], float (&h)[8], float (&p)[8]) {
      const int EL = dpp_i<DPP_WSHR1>(E);   // left lane's exponent (lane0->0)
      const int d = E - EL;             // block-constant reconcile shift
      #pragma unroll
      for (int j = 0; j < 8; ++j) {
        const float p1 = dpp_f<DPP_WSHR1>(A1);   // left A1 (state 3i-2)
        const float p2 = dpp_f<DPP_WSHR1>(A2);   // left A2 (state 3i-1)
        const float p1p = ldexpf(p1, d);
        const float p2p = ldexpf(p2, d);
        const float q0 = evenLane ? p[j] : g[j];
        const float q1 = evenLane ? g[j] : p[j];
        const float q2 = evenLane ? p[j] : h[j];
        const float t0 = q0 * fmaf(m0, p1p, A0 + p2p);
        const float t1 = q1 * fmaf(m1, p2p, A1 + A0);
        const float t2 = q2 * fmaf(m2, A0, A2 + A1);
        A0 = t0; A1 = t1; A2 = t2;
      }
      // per-lane rescale: keep lane max ~2^0, fold into E
      const float mx = fmaxf(fmaxf(A0, A1), A2);
      int ee = (int)((__float_as_uint(mx) >> 23) & 255u) - 127;
      const bool z = (mx == 0.f);
      ee = z ? 0 : ee;
      A0 = ldexpf(A0, -ee); A1 = ldexpf(A1, -ee); A2 = ldexpf(A2, -ee);
      E = z ? EL : (E - ee);            // virgin lanes track left neighbor's E
    };

    // two named gather sets (compile-time indexing only, rule #20);
    // gathers for block i+1 issue before the DP of block i (latency hidden)
    float gaA[8], gbA[8], pbA[8], gaB[8], gbB[8], pbB[8];
    waitFlag(0); gath(gaA, gbA, pbA, 0);
    for (int i = 0; i < 64; i += 2) {
      waitFlag(i + 1); gath(gaB, gbB, pbB, i + 1);
      stepG(gaA, gbA, pbA);             // block i
      consSet(i + 1);
      if (i + 2 < 64) { waitFlag(i + 2); gath(gaA, gbA, pbA, i + 2); }
      stepG(gaB, gbB, pbB);             // block i+1
      consSet(i + 2);
    }

    __syncthreads();                    // the ONLY full barrier (epilogue)

    // loss = ln2 * (S - (log2(A159+A160) - E)); lane 53: A0=s159, A1=s160
    if (lane == 53) {
      const float Stot = comb[1] + comb[2] + comb[3];
      out[b] = LN2_ * (Stot - (LOG2F(A0 + A1) - (float)E));
    }
  } else {
    // ---- producer: every-3rd 8-row block, 2-owned-block register lead ----
    const int w = wid - 1;              // 0..2; owns blocks w, w+3, ...
    const int rgrp = lane >> 3, j16 = lane & 7;
    float4 S0[4], S1[4];
    float Sacc = 0.f;                   // per-lane partial: sum log2(rowsum)

    auto loadB = [&](float4 (&S)[4], int blk) {
      const float4* src =
          (const float4*)(gp + (size_t)(8 * blk + rgrp) * C_) + 4 * j16;
      #pragma unroll
      for (int k = 0; k < 4; ++k) S[k] = src[k];
    };
    auto waitSlot = [&](int j) {        // slot j&15 holds block j-16
      if (j >= RING_) {
        while (__hip_atomic_load(&cons, __ATOMIC_RELAXED,
                                 __HIP_MEMORY_SCOPE_WORKGROUP) < j - (RING_ - 1))
          __builtin_amdgcn_s_sleep(8);
      }
    };
    auto proc = [&](float4 (&S)[4], int j) {  // eps+rowsum+stage+publish
      float* slot = ring + (j & (RING_ - 1)) * 1024;
      float4* wd = (float4*)(slot + rgrp * C_ + 16 * j16);
      float s = 0.f;
      #pragma unroll
      for (int k = 0; k < 4; ++k) {
        float4 v = S[k];
        v.x += EPS_; v.y += EPS_; v.z += EPS_; v.w += EPS_;
        wd[k] = v;
        s += (v.x + v.y) + (v.z + v.w);
      }
      s += dpp_f<DPP_XOR1>(s);
      s += dpp_f<DPP_XOR2>(s);
      s += dpp_f<DPP_HMIRR>(s);         // 8 lanes of the row share the sum
      Sacc += LOG2F(s);                 // 8x redundant; divided out at end
      asm volatile("s_waitcnt lgkmcnt(0)" ::: "memory");  // data before flag
      if (lane == 0)
        __hip_atomic_store(&flags[j], 1, __ATOMIC_RELEASE,
                           __HIP_MEMORY_SCOPE_WORKGROUP);
    };

    int j = w;
    loadB(S0, j);
    if (j + 3 < 64) loadB(S1, j + 3);
    while (true) {
      waitSlot(j); proc(S0, j);
      if (j + 6 < 64) loadB(S0, j + 6);
      j += 3;
      if (j >= 64) break;
      waitSlot(j); proc(S1, j);
      if (j + 6 < 64) loadB(S1, j + 6);
      j += 3;
      if (j >= 64) break;
    }

    // denominator partial (each row counted 8x -> *0.125)
    float s = Sacc;
    s += dpp_f<DPP_XOR1>(s);
    s += dpp_f<DPP_XOR2>(s);
    s += dpp_f<DPP_HMIRR>(s);
    s += dpp_f<DPP_MIRR>(s);
    s += __shfl_xor(s, 16, 64);
    s += __shfl_xor(s, 32, 64);
    if (lane == 0) comb[wid] = s * 0.125f;

    __syncthreads();                    // matches consumer's epilogue barrier
  }
}

extern "C" void kernel_launch(void* const* d_in, const int* in_sizes, int n_in,
                              void* d_out, int out_size, void* d_ws, size_t ws_size,
                              hipStream_t stream) {
  const int*   labels = (const int*)d_in[0];    // y_true [B,L]
  const float* y_pred = (const float*)d_in[1];  // y_pred [B,T,C]
  float*       out    = (float*)d_out;          // [B,1]
  ctc_fused<<<dim3(B_), dim3(256), 0, stream>>>(labels, y_pred, out);
}